// Round 1
// baseline (301.230 us; speedup 1.0000x reference)
//
#include <hip/hip_runtime.h>
#include <math.h>

#define BB 8
#define MI 16
#define NN 409600          // 640*640
#define CEPS 1e-12f
#define GPB 200            // blocks per image; 2048 px/block
#define TPB 256

// ws float layout — no zero-init needed (every slot written before read):
//   PS:  k_sums partials [b][blk][v], v = m*5+c (c<4 channel sums, c=4 count)
//   PP:  k_pull partials [b][blk][v], v = m*2+c (c=0 loss sum, c=1 count)
// G/valid are recomputed redundantly (identical summation order) in k_pull
// and k_final prologues from PS — removes the k_finG launch.
#define WS_PS   0
#define WS_PP   (BB*GPB*80)            // 128000

// k_sums v2: each wave reads a DISTINCT 512-px slice (no 4x redundant L1
// traffic) and accumulates ALL 16 ids in 64 statically-indexed VGPRs.
// Counts on the scalar pipe via ballot+popc. Block reduce in 4 LDS rounds.
__global__ __launch_bounds__(TPB, 4) void k_sums(
    const float* __restrict__ outputs, const int* __restrict__ gt_kernels,
    float* __restrict__ ws) {
  __shared__ float red[4][64][17];     // stride-17: conflict-free columns
  __shared__ float part2[4][16];
  __shared__ float cbuf[4][MI];
  __shared__ float obuf[80];
  const int b = blockIdx.y, blk = blockIdx.x, tid = threadIdx.x;
  const int wv = tid >> 6, lane = tid & 63;

  float acc[64];                       // acc[m*4+c]: id m, channel c
#pragma unroll
  for (int i = 0; i < 64; i++) acc[i] = 0.f;
  unsigned int cnt[16];
#pragma unroll
  for (int m = 0; m < MI; m++) cnt[m] = 0u;

  const float* s0 = outputs + (size_t)(b * 8 + 4) * NN;
  const int* gkb = gt_kernels + (size_t)b * NN;

#pragma unroll
  for (int it = 0; it < 2; it++) {
    const int pix = blk * 2048 + wv * 512 + it * 256 + lane * 4;
    const int4 id4 = *(const int4*)(gkb + pix);
    const float4 x0 = *(const float4*)(s0 + pix);
    const float4 x1 = *(const float4*)(s0 + NN + pix);
    const float4 x2 = *(const float4*)(s0 + 2 * NN + pix);
    const float4 x3 = *(const float4*)(s0 + 3 * NN + pix);
#define SLOTK(IDC, XC)                                                       \
    {                                                                        \
      const int id = id4.IDC;                                                \
      _Pragma("unroll")                                                      \
      for (int m = 0; m < MI; m++) {                                         \
        const bool e = (id == m);                                            \
        cnt[m] += (unsigned)__popcll(__ballot(e));   /* scalar pipe */       \
        const float f = e ? 1.f : 0.f;                                       \
        acc[m * 4 + 0] += f * x0.XC;                                         \
        acc[m * 4 + 1] += f * x1.XC;                                         \
        acc[m * 4 + 2] += f * x2.XC;                                         \
        acc[m * 4 + 3] += f * x3.XC;                                         \
      }                                                                      \
    }
    SLOTK(x, x) SLOTK(y, y) SLOTK(z, z) SLOTK(w, w)
#undef SLOTK
  }

  if (lane == 0) {
#pragma unroll
    for (int m = 0; m < MI; m++) cbuf[wv][m] = (float)cnt[m];
  }

  // 4 rounds: round r reduces values acc[r*16 .. r*16+15] (ids 4r..4r+3)
#pragma unroll
  for (int r = 0; r < 4; r++) {
#pragma unroll
    for (int k = 0; k < 16; k++) red[wv][lane][k] = acc[r * 16 + k];
    __syncthreads();
    if (tid < 64) {
      const int k = tid & 15, q = tid >> 4;
      float s = 0.f;
#pragma unroll
      for (int l = 0; l < 16; l++) {
        const int ln = q * 16 + l;
        s += red[0][ln][k] + red[1][ln][k] + red[2][ln][k] + red[3][ln][k];
      }
      part2[q][k] = s;
    }
    __syncthreads();
    if (tid < 16) {
      const int m = 4 * r + (tid >> 2), c = tid & 3;
      obuf[m * 5 + c] = part2[0][tid] + part2[1][tid] + part2[2][tid] + part2[3][tid];
    }
    __syncthreads();
  }
  if (tid < 16)
    obuf[tid * 5 + 4] = cbuf[0][tid] + cbuf[1][tid] + cbuf[2][tid] + cbuf[3][tid];
  __syncthreads();
  if (tid < 80)
    ws[WS_PS + (size_t)(b * GPB + blk) * 80 + tid] = obuf[tid];   // contiguous
}

// k_pull: G computed in-block from PS partials (L2-hot, ~0.3us), then the
// verified v1 main loop: dist/log once per pixel; al[16] register
// accumulators, counts on the scalar pipe. No atomics.
__global__ __launch_bounds__(TPB, 6) void k_pull(
    const float* __restrict__ outputs, const int* __restrict__ gt_texts,
    float* __restrict__ ws) {
  __shared__ float4 sG[MI];
  __shared__ float red[4][64][17];
  __shared__ float cbuf[4][MI];
  __shared__ float gpart[3][80];
  __shared__ float tot80[80];
  const int b = blockIdx.y, blk = blockIdx.x, tid = threadIdx.x;
  const int wv = tid >> 6, lane = tid & 63;

  // ---- G prologue: reduce PS over 200 blocks (same order as k_final) ----
  {
    const int v = tid % 80, h = tid / 80;
    if (h < 3) {
      const int nb = (h < 2) ? 67 : 66;
      const float* src = ws + WS_PS + (size_t)(b * GPB + h * 67) * 80 + v;
      float s = 0.f;
      for (int k = 0; k < nb; k++) s += src[(size_t)k * 80];
      gpart[h][v] = s;
    }
    __syncthreads();
    if (tid < 80) tot80[tid] = gpart[0][tid] + gpart[1][tid] + gpart[2][tid];
    __syncthreads();
    if (tid < MI) {
      const float cntk = tot80[tid * 5 + 4];
      const float inv = 1.f / fmaxf(cntk, 1.f);
      float4 g;
      g.x = tot80[tid * 5 + 0] * inv;
      g.y = tot80[tid * 5 + 1] * inv;
      g.z = tot80[tid * 5 + 2] * inv;
      g.w = tot80[tid * 5 + 3] * inv;
      sG[tid] = g;
    }
    __syncthreads();
  }

  float al[16];
#pragma unroll
  for (int m = 0; m < MI; m++) al[m] = 0.f;
  unsigned int cw[16];
#pragma unroll
  for (int m = 0; m < MI; m++) cw[m] = 0u;

  const float* s0 = outputs + (size_t)(b * 8 + 4) * NN;
  const int* ttb = gt_texts + (size_t)b * NN;

#pragma unroll
  for (int it = 0; it < 2; it++) {
    const int pix = blk * 2048 + it * 1024 + tid * 4;
    const int4 id4 = *(const int4*)(ttb + pix);
    const float4 x0 = *(const float4*)(s0 + pix);
    const float4 x1 = *(const float4*)(s0 + NN + pix);
    const float4 x2 = *(const float4*)(s0 + 2 * NN + pix);
    const float4 x3 = *(const float4*)(s0 + 3 * NN + pix);
#define SLOTP(IDC, XC)                                                       \
    {                                                                        \
      const int id = id4.IDC;                                                \
      const float4 g = sG[id];                                               \
      const float d0 = x0.XC - g.x, d1 = x1.XC - g.y;                        \
      const float d2 = x2.XC - g.z, d3 = x3.XC - g.w;                        \
      const float dist = sqrtf(d0*d0 + d1*d1 + d2*d2 + d3*d3 + CEPS) - 0.5f; \
      const float dm = fmaxf(dist, 0.f);                                     \
      const float l = __logf(1.f + dm * dm);                                 \
      _Pragma("unroll")                                                      \
      for (int m = 0; m < MI; m++) {                                         \
        const bool e = (id == m);                                            \
        cw[m] += (unsigned)__popcll(__ballot(e));    /* scalar pipe */       \
        al[m] += e ? l : 0.f;                                                \
      }                                                                      \
    }
    SLOTP(x, x) SLOTP(y, y) SLOTP(z, z) SLOTP(w, w)
#undef SLOTP
  }

#pragma unroll
  for (int v = 0; v < 16; v++) red[wv][lane][v] = al[v];
  if (lane == 0) {
#pragma unroll
    for (int m = 0; m < MI; m++) cbuf[wv][m] = (float)cw[m];
  }
  __syncthreads();
  if (tid < 32) {
    const int m = tid >> 1, c = tid & 1;
    float s = 0.f;
    if (c == 0) {
#pragma unroll
      for (int w = 0; w < 4; w++)
#pragma unroll 8
        for (int l = 0; l < 64; l++) s += red[w][(l + tid) & 63][m];
    } else {
      s = cbuf[0][m] + cbuf[1][m] + cbuf[2][m] + cbuf[3][m];
    }
    ws[WS_PP + (size_t)(b * GPB + blk) * 32 + tid] = s;   // contiguous
  }
}

__global__ void k_final(const float* __restrict__ ws, float* __restrict__ out) {
  __shared__ float gpart[3][80];
  __shared__ float tot80[80];
  __shared__ float part[8][32];
  __shared__ float tot[32];
  __shared__ float sG[MI * 4];
  __shared__ float svalid[MI];
  const int b = blockIdx.x, t = threadIdx.x;   // 256 threads, one block per b

  // ---- G + valid prologue (identical summation order to k_pull) ----
  {
    const int v = t % 80, h = t / 80;
    if (h < 3) {
      const int nb = (h < 2) ? 67 : 66;
      const float* src = ws + WS_PS + (size_t)(b * GPB + h * 67) * 80 + v;
      float s = 0.f;
      for (int k = 0; k < nb; k++) s += src[(size_t)k * 80];
      gpart[h][v] = s;
    }
    __syncthreads();
    if (t < 80) tot80[t] = gpart[0][t] + gpart[1][t] + gpart[2][t];
    __syncthreads();
    if (t < MI) {
      const float cntk = tot80[t * 5 + 4];
      const float inv = 1.f / fmaxf(cntk, 1.f);
      sG[t * 4 + 0] = tot80[t * 5 + 0] * inv;
      sG[t * 4 + 1] = tot80[t * 5 + 1] * inv;
      sG[t * 4 + 2] = tot80[t * 5 + 2] * inv;
      sG[t * 4 + 3] = tot80[t * 5 + 3] * inv;
      svalid[t] = (cntk > 0.f && t >= 1) ? 1.f : 0.f;
    }
    __syncthreads();
  }

  // ---- PP reduce ----
  const int v = t & 31, h = t >> 5;            // 8 chunks of 25 blocks
  float s = 0.f;
  const float* src = ws + WS_PP + (size_t)(b * GPB + h * 25) * 32 + v;
#pragma unroll                                  // FULL unroll: independent loads
  for (int k = 0; k < 25; k++) s += src[(size_t)k * 32];
  part[h][v] = s;
  __syncthreads();
  if (t < 32) {
    float x = 0.f;
#pragma unroll
    for (int hh = 0; hh < 8; hh++) x += part[hh][t];
    tot[t] = x;
  }
  __syncthreads();
  if (t == 0) {
    float nv = 0.f;
    for (int m = 0; m < MI; m++) nv += svalid[m];
    float pull = 0.f;
    for (int m = 0; m < MI; m++) {
      const float per = tot[m * 2] / fmaxf(tot[m * 2 + 1], 1.f);
      pull += per * svalid[m];
    }
    pull /= fmaxf(nv, 1.f);
    float push = 0.f;
    for (int i = 0; i < MI; i++) {
      if (svalid[i] == 0.f) continue;
      for (int j = i + 1; j < MI; j++) {
        if (svalid[j] == 0.f) continue;
        float d2 = CEPS;
        for (int c = 0; c < 4; c++) {
          const float df = sG[i * 4 + c] - sG[j * 4 + c];
          d2 += df * df;
        }
        const float dk = sqrtf(d2);
        const float tt = fmaxf(3.f - dk, 0.f);
        push += log1pf(tt * tt);
      }
    }
    const float denom = nv * (nv - 1.f);
    push = (nv > 1.f) ? push / fmaxf(denom, 1.f) : 0.f;
    out[b] = pull;
    out[BB + b] = push;
  }
}

extern "C" void kernel_launch(void* const* d_in, const int* in_sizes, int n_in,
                              void* d_out, int out_size, void* d_ws, size_t ws_size,
                              hipStream_t stream) {
  const float* outputs = (const float*)d_in[0];
  const int* gt_texts = (const int*)d_in[1];
  const int* gt_kernels = (const int*)d_in[2];
  float* ws = (float*)d_ws;
  float* out = (float*)d_out;

  dim3 grid(GPB, BB);
  k_sums<<<grid, TPB, 0, stream>>>(outputs, gt_kernels, ws);
  k_pull<<<grid, TPB, 0, stream>>>(outputs, gt_texts, ws);
  k_final<<<BB, 256, 0, stream>>>(ws, out);
}

// Round 2
// 253.009 us; speedup vs baseline: 1.1906x; 1.1906x over previous
//
#include <hip/hip_runtime.h>
#include <math.h>

#define BB 8
#define MI 16
#define NN 409600          // 640*640
#define CEPS 1e-12f
#define GPB 200            // blocks per image; 2048 px/block
#define TPB 256

// ws float layout — no zero-init needed (every slot written before read):
//   PS:  k_sums partials [b][blk][v], v = m*5+c (c<4 channel sums, c=4 count)
//   G:   [b][m][4]  (float4 aligned)
//   VAL: [b][m]
//   PP:  k_pull partials [b][blk][v], v = m*2+c (c=0 loss sum, c=1 count)
#define WS_PS   0
#define WS_G    (BB*GPB*80)            // 128000
#define WS_VAL  (WS_G + BB*MI*4)
#define WS_PP   (WS_VAL + BB*MI)

// k_sums v2: each wave reads a DISTINCT 512-px slice (no 4x redundant L1
// traffic vs v1) and accumulates ALL 16 ids in 64 statically-indexed VGPRs.
// Counts on the scalar pipe via ballot+popc. Block reduce in 4 LDS rounds.
// No atomics anywhere.
__global__ __launch_bounds__(TPB, 4) void k_sums(
    const float* __restrict__ outputs, const int* __restrict__ gt_kernels,
    float* __restrict__ ws) {
  __shared__ float red[4][64][17];     // stride-17: conflict-free columns
  __shared__ float part2[4][16];
  __shared__ float cbuf[4][MI];
  __shared__ float obuf[80];
  const int b = blockIdx.y, blk = blockIdx.x, tid = threadIdx.x;
  const int wv = tid >> 6, lane = tid & 63;

  float acc[64];                       // acc[m*4+c]: id m, channel c
#pragma unroll
  for (int i = 0; i < 64; i++) acc[i] = 0.f;
  unsigned int cnt[16];
#pragma unroll
  for (int m = 0; m < MI; m++) cnt[m] = 0u;

  const float* s0 = outputs + (size_t)(b * 8 + 4) * NN;
  const int* gkb = gt_kernels + (size_t)b * NN;

#pragma unroll
  for (int it = 0; it < 2; it++) {
    const int pix = blk * 2048 + wv * 512 + it * 256 + lane * 4;
    const int4 id4 = *(const int4*)(gkb + pix);
    const float4 x0 = *(const float4*)(s0 + pix);
    const float4 x1 = *(const float4*)(s0 + NN + pix);
    const float4 x2 = *(const float4*)(s0 + 2 * NN + pix);
    const float4 x3 = *(const float4*)(s0 + 3 * NN + pix);
#define SLOTK(IDC, XC)                                                       \
    {                                                                        \
      const int id = id4.IDC;                                                \
      _Pragma("unroll")                                                      \
      for (int m = 0; m < MI; m++) {                                         \
        const bool e = (id == m);                                            \
        cnt[m] += (unsigned)__popcll(__ballot(e));   /* scalar pipe */       \
        const float f = e ? 1.f : 0.f;                                       \
        acc[m * 4 + 0] += f * x0.XC;                                         \
        acc[m * 4 + 1] += f * x1.XC;                                         \
        acc[m * 4 + 2] += f * x2.XC;                                         \
        acc[m * 4 + 3] += f * x3.XC;                                         \
      }                                                                      \
    }
    SLOTK(x, x) SLOTK(y, y) SLOTK(z, z) SLOTK(w, w)
#undef SLOTK
  }

  if (lane == 0) {
#pragma unroll
    for (int m = 0; m < MI; m++) cbuf[wv][m] = (float)cnt[m];
  }

  // 4 rounds: round r reduces values acc[r*16 .. r*16+15] (ids 4r..4r+3)
#pragma unroll
  for (int r = 0; r < 4; r++) {
#pragma unroll
    for (int k = 0; k < 16; k++) red[wv][lane][k] = acc[r * 16 + k];
    __syncthreads();
    if (tid < 64) {
      const int k = tid & 15, q = tid >> 4;
      float s = 0.f;
#pragma unroll
      for (int l = 0; l < 16; l++) {
        const int ln = q * 16 + l;
        s += red[0][ln][k] + red[1][ln][k] + red[2][ln][k] + red[3][ln][k];
      }
      part2[q][k] = s;
    }
    __syncthreads();
    if (tid < 16) {
      const int m = 4 * r + (tid >> 2), c = tid & 3;
      obuf[m * 5 + c] = part2[0][tid] + part2[1][tid] + part2[2][tid] + part2[3][tid];
    }
    __syncthreads();
  }
  if (tid < 16)
    obuf[tid * 5 + 4] = cbuf[0][tid] + cbuf[1][tid] + cbuf[2][tid] + cbuf[3][tid];
  __syncthreads();
  if (tid < 80)
    ws[WS_PS + (size_t)(b * GPB + blk) * 80 + tid] = obuf[tid];   // contiguous
}

// k_finG: reduce PS over 200 blocks. FULL unroll (compile-time 40) keeps all
// loads independent & in flight — the round-1 runtime-bound loop serialized
// into a latency chain (73us). Never again.
__global__ void k_finG(float* __restrict__ ws) {
  __shared__ float part[5][80];
  __shared__ float tot[80];
  const int b = blockIdx.x, t = threadIdx.x;   // 400 threads
  const int v = t % 80, h = t / 80;            // h < 5, 40 blocks each
  float s = 0.f;
  const float* src = ws + WS_PS + (size_t)(b * GPB + h * 40) * 80 + v;
#pragma unroll                                  // FULL unroll: independent loads
  for (int k = 0; k < 40; k++) s += src[(size_t)k * 80];
  part[h][v] = s;
  __syncthreads();
  if (t < 80) tot[t] = part[0][t] + part[1][t] + part[2][t] + part[3][t] + part[4][t];
  __syncthreads();
  if (t < MI) {
    const float cnt = tot[t * 5 + 4];
    const float inv = 1.f / fmaxf(cnt, 1.f);
    float4 g;
    g.x = tot[t * 5 + 0] * inv;
    g.y = tot[t * 5 + 1] * inv;
    g.z = tot[t * 5 + 2] * inv;
    g.w = tot[t * 5 + 3] * inv;
    ((float4*)(ws + WS_G))[b * MI + t] = g;
    ws[WS_VAL + b * MI + t] = (cnt > 0.f && t >= 1) ? 1.f : 0.f;
  }
}

// k_pull: dist/log once per pixel; al[16] register accumulators (scalar l),
// counts on the scalar pipe. No atomics.
__global__ __launch_bounds__(TPB, 6) void k_pull(
    const float* __restrict__ outputs, const int* __restrict__ gt_texts,
    float* __restrict__ ws) {
  __shared__ float4 sG[MI];
  __shared__ float red[4][64][17];
  __shared__ float cbuf[4][MI];
  const int b = blockIdx.y, blk = blockIdx.x, tid = threadIdx.x;
  const int wv = tid >> 6, lane = tid & 63;
  if (tid < MI) sG[tid] = ((const float4*)(ws + WS_G))[b * MI + tid];
  __syncthreads();

  float al[16];
#pragma unroll
  for (int m = 0; m < MI; m++) al[m] = 0.f;
  unsigned int cw[16];
#pragma unroll
  for (int m = 0; m < MI; m++) cw[m] = 0u;

  const float* s0 = outputs + (size_t)(b * 8 + 4) * NN;
  const int* ttb = gt_texts + (size_t)b * NN;

#pragma unroll
  for (int it = 0; it < 2; it++) {
    const int pix = blk * 2048 + it * 1024 + tid * 4;
    const int4 id4 = *(const int4*)(ttb + pix);
    const float4 x0 = *(const float4*)(s0 + pix);
    const float4 x1 = *(const float4*)(s0 + NN + pix);
    const float4 x2 = *(const float4*)(s0 + 2 * NN + pix);
    const float4 x3 = *(const float4*)(s0 + 3 * NN + pix);
#define SLOTP(IDC, XC)                                                       \
    {                                                                        \
      const int id = id4.IDC;                                                \
      const float4 g = sG[id];                                               \
      const float d0 = x0.XC - g.x, d1 = x1.XC - g.y;                        \
      const float d2 = x2.XC - g.z, d3 = x3.XC - g.w;                        \
      const float dist = sqrtf(d0*d0 + d1*d1 + d2*d2 + d3*d3 + CEPS) - 0.5f; \
      const float dm = fmaxf(dist, 0.f);                                     \
      const float l = __logf(1.f + dm * dm);                                 \
      _Pragma("unroll")                                                      \
      for (int m = 0; m < MI; m++) {                                         \
        const bool e = (id == m);                                            \
        cw[m] += (unsigned)__popcll(__ballot(e));    /* scalar pipe */       \
        al[m] += e ? l : 0.f;                                                \
      }                                                                      \
    }
    SLOTP(x, x) SLOTP(y, y) SLOTP(z, z) SLOTP(w, w)
#undef SLOTP
  }

#pragma unroll
  for (int v = 0; v < 16; v++) red[wv][lane][v] = al[v];
  if (lane == 0) {
#pragma unroll
    for (int m = 0; m < MI; m++) cbuf[wv][m] = (float)cw[m];
  }
  __syncthreads();
  if (tid < 32) {
    const int m = tid >> 1, c = tid & 1;
    float s = 0.f;
    if (c == 0) {
#pragma unroll
      for (int w = 0; w < 4; w++)
#pragma unroll 8
        for (int l = 0; l < 64; l++) s += red[w][(l + tid) & 63][m];
    } else {
      s = cbuf[0][m] + cbuf[1][m] + cbuf[2][m] + cbuf[3][m];
    }
    ws[WS_PP + (size_t)(b * GPB + blk) * 32 + tid] = s;   // contiguous per block
  }
}

__global__ void k_final(const float* __restrict__ ws, float* __restrict__ out) {
  __shared__ float part[8][32];
  __shared__ float tot[32];
  const int b = blockIdx.x, t = threadIdx.x;   // 256 threads, one block per b
  const int v = t & 31, h = t >> 5;            // 8 chunks of 25 blocks
  float s = 0.f;
  const float* src = ws + WS_PP + (size_t)(b * GPB + h * 25) * 32 + v;
#pragma unroll                                  // FULL unroll: independent loads
  for (int k = 0; k < 25; k++) s += src[(size_t)k * 32];
  part[h][v] = s;
  __syncthreads();
  if (t < 32) {
    float x = 0.f;
#pragma unroll
    for (int hh = 0; hh < 8; hh++) x += part[hh][t];
    tot[t] = x;
  }
  __syncthreads();
  if (t == 0) {
    const float* G = ws + WS_G;
    const float* valid = ws + WS_VAL;
    float nv = 0.f;
    for (int m = 0; m < MI; m++) nv += valid[b * MI + m];
    float pull = 0.f;
    for (int m = 0; m < MI; m++) {
      const float per = tot[m * 2] / fmaxf(tot[m * 2 + 1], 1.f);
      pull += per * valid[b * MI + m];
    }
    pull /= fmaxf(nv, 1.f);
    float push = 0.f;
    for (int i = 0; i < MI; i++) {
      if (valid[b * MI + i] == 0.f) continue;
      for (int j = i + 1; j < MI; j++) {
        if (valid[b * MI + j] == 0.f) continue;
        float d2 = CEPS;
        for (int c = 0; c < 4; c++) {
          const float df = G[(b * MI + i) * 4 + c] - G[(b * MI + j) * 4 + c];
          d2 += df * df;
        }
        const float dk = sqrtf(d2);
        const float tt = fmaxf(3.f - dk, 0.f);
        push += log1pf(tt * tt);
      }
    }
    const float denom = nv * (nv - 1.f);
    push = (nv > 1.f) ? push / fmaxf(denom, 1.f) : 0.f;
    out[b] = pull;
    out[BB + b] = push;
  }
}

extern "C" void kernel_launch(void* const* d_in, const int* in_sizes, int n_in,
                              void* d_out, int out_size, void* d_ws, size_t ws_size,
                              hipStream_t stream) {
  const float* outputs = (const float*)d_in[0];
  const int* gt_texts = (const int*)d_in[1];
  const int* gt_kernels = (const int*)d_in[2];
  float* ws = (float*)d_ws;
  float* out = (float*)d_out;

  dim3 grid(GPB, BB);
  k_sums<<<grid, TPB, 0, stream>>>(outputs, gt_kernels, ws);
  k_finG<<<BB, 400, 0, stream>>>(ws);
  k_pull<<<grid, TPB, 0, stream>>>(outputs, gt_texts, ws);
  k_final<<<BB, 256, 0, stream>>>(ws, out);
}

// Round 3
// 250.966 us; speedup vs baseline: 1.2003x; 1.0081x over previous
//
#include <hip/hip_runtime.h>
#include <math.h>

#define BB 8
#define MI 16
#define NN 409600          // 640*640
#define CEPS 1e-12f
#define GPB 200            // blocks per image; 2048 px/block
#define TPB 256

// ws float layout — no zero-init needed (every slot written before read):
//   PS:  k_sums partials [b][blk][v], v = m*5+c (c<4 channel sums, c=4 count)
//   PP:  k_pull partials [b][blk][v], v = m*2+c (c=0 loss sum, c=1 count)
// G/valid are recomputed redundantly (IDENTICAL summation order) in k_pull
// and k_final prologues from PS — removes the k_finG launch. All prologue
// reduction loops have COMPILE-TIME trip counts (67/66) -> full unroll ->
// independent loads (the R1 runtime-bound loop serialized into a 73us
// latency chain; never again).
#define WS_PS   0
#define WS_PP   (BB*GPB*80)            // 128000

// k_sums v1 (R0-proven): wave w owns ids 4w..4w+3 (16 acc VGPRs). Every wave
// streams the whole 2048-px chunk (redundant reads are L1/L2-absorbed; the
// 64-acc variant traded occupancy 6->4 and measured slower). Counts on the
// scalar pipe via ballot+popc. No atomics anywhere.
__global__ __launch_bounds__(TPB, 6) void k_sums(
    const float* __restrict__ outputs, const int* __restrict__ gt_kernels,
    float* __restrict__ ws) {
  __shared__ float red[4][64][17];     // stride-17: conflict-free columns
  __shared__ float cbuf[MI];
  const int b = blockIdx.y, blk = blockIdx.x, tid = threadIdx.x;
  const int wv = tid >> 6, lane = tid & 63;
  const int mb = wv * 4;

  float acc[16];                       // acc[c*4+j]: channel c, id mb+j
#pragma unroll
  for (int i = 0; i < 16; i++) acc[i] = 0.f;
  unsigned int cnt[4] = {0u, 0u, 0u, 0u};

  const float* s0 = outputs + (size_t)(b * 8 + 4) * NN;
  const int* gkb = gt_kernels + (size_t)b * NN;

#pragma unroll 2
  for (int it = 0; it < 8; it++) {
    const int pix = blk * 2048 + it * 256 + lane * 4;
    const int4 id4 = *(const int4*)(gkb + pix);
    const float4 x0 = *(const float4*)(s0 + pix);
    const float4 x1 = *(const float4*)(s0 + NN + pix);
    const float4 x2 = *(const float4*)(s0 + 2 * NN + pix);
    const float4 x3 = *(const float4*)(s0 + 3 * NN + pix);
#define SLOTK(IDC, XC)                                                       \
    {                                                                        \
      const int id = id4.IDC - mb;                                           \
      _Pragma("unroll")                                                      \
      for (int j = 0; j < 4; j++) {                                          \
        const bool e = (id == j);                                            \
        cnt[j] += (unsigned)__popcll(__ballot(e));   /* scalar pipe */       \
        const float f = e ? 1.f : 0.f;                                       \
        acc[0 * 4 + j] += f * x0.XC;                                         \
        acc[1 * 4 + j] += f * x1.XC;                                         \
        acc[2 * 4 + j] += f * x2.XC;                                         \
        acc[3 * 4 + j] += f * x3.XC;                                         \
      }                                                                      \
    }
    SLOTK(x, x) SLOTK(y, y) SLOTK(z, z) SLOTK(w, w)
#undef SLOTK
  }

  // flush: per-lane partials -> LDS, then 80 threads reduce 64 lanes each
#pragma unroll
  for (int v = 0; v < 16; v++) red[wv][lane][v] = acc[v];
  if (lane == 0) {
#pragma unroll
    for (int j = 0; j < 4; j++) cbuf[mb + j] = (float)cnt[j];
  }
  __syncthreads();
  if (tid < 80) {
    const int m = tid / 5, c = tid % 5;
    const int w = m >> 2, j = m & 3;
    float s;
    if (c < 4) {
      const int vi = c * 4 + j;
      s = 0.f;
#pragma unroll 8
      for (int l = 0; l < 64; l++) s += red[w][(l + tid) & 63][vi];
    } else {
      s = cbuf[m];
    }
    ws[WS_PS + (size_t)(b * GPB + blk) * 80 + tid] = s;   // contiguous per block
  }
}

// k_pull: G computed in-block from PS partials (L2-hot, prologue hidden by
// the 5 other resident blocks' main loops), then the verified main loop:
// dist/log once per pixel; al[16] register accumulators, counts on the
// scalar pipe. No atomics.
__global__ __launch_bounds__(TPB, 6) void k_pull(
    const float* __restrict__ outputs, const int* __restrict__ gt_texts,
    float* __restrict__ ws) {
  __shared__ float4 sG[MI];
  __shared__ float red[4][64][17];
  __shared__ float cbuf[4][MI];
  __shared__ float gpart[3][80];
  __shared__ float tot80[80];
  const int b = blockIdx.y, blk = blockIdx.x, tid = threadIdx.x;
  const int wv = tid >> 6, lane = tid & 63;

  // ---- G prologue: reduce PS over 200 blocks (same order as k_final) ----
  {
    const int v = tid % 80, h = tid / 80;
    if (h < 2) {
      const float* src = ws + WS_PS + (size_t)(b * GPB + h * 67) * 80 + v;
      float s = 0.f;
#pragma unroll                                  // FULL unroll: independent loads
      for (int k = 0; k < 67; k++) s += src[(size_t)k * 80];
      gpart[h][v] = s;
    } else if (h == 2) {
      const float* src = ws + WS_PS + (size_t)(b * GPB + 134) * 80 + v;
      float s = 0.f;
#pragma unroll                                  // FULL unroll: independent loads
      for (int k = 0; k < 66; k++) s += src[(size_t)k * 80];
      gpart[2][v] = s;
    }
    __syncthreads();
    if (tid < 80) tot80[tid] = gpart[0][tid] + gpart[1][tid] + gpart[2][tid];
    __syncthreads();
    if (tid < MI) {
      const float cntk = tot80[tid * 5 + 4];
      const float inv = 1.f / fmaxf(cntk, 1.f);
      float4 g;
      g.x = tot80[tid * 5 + 0] * inv;
      g.y = tot80[tid * 5 + 1] * inv;
      g.z = tot80[tid * 5 + 2] * inv;
      g.w = tot80[tid * 5 + 3] * inv;
      sG[tid] = g;
    }
    __syncthreads();
  }

  float al[16];
#pragma unroll
  for (int m = 0; m < MI; m++) al[m] = 0.f;
  unsigned int cw[16];
#pragma unroll
  for (int m = 0; m < MI; m++) cw[m] = 0u;

  const float* s0 = outputs + (size_t)(b * 8 + 4) * NN;
  const int* ttb = gt_texts + (size_t)b * NN;

#pragma unroll
  for (int it = 0; it < 2; it++) {
    const int pix = blk * 2048 + it * 1024 + tid * 4;
    const int4 id4 = *(const int4*)(ttb + pix);
    const float4 x0 = *(const float4*)(s0 + pix);
    const float4 x1 = *(const float4*)(s0 + NN + pix);
    const float4 x2 = *(const float4*)(s0 + 2 * NN + pix);
    const float4 x3 = *(const float4*)(s0 + 3 * NN + pix);
#define SLOTP(IDC, XC)                                                       \
    {                                                                        \
      const int id = id4.IDC;                                                \
      const float4 g = sG[id];                                               \
      const float d0 = x0.XC - g.x, d1 = x1.XC - g.y;                        \
      const float d2 = x2.XC - g.z, d3 = x3.XC - g.w;                        \
      const float dist = sqrtf(d0*d0 + d1*d1 + d2*d2 + d3*d3 + CEPS) - 0.5f; \
      const float dm = fmaxf(dist, 0.f);                                     \
      const float l = __logf(1.f + dm * dm);                                 \
      _Pragma("unroll")                                                      \
      for (int m = 0; m < MI; m++) {                                         \
        const bool e = (id == m);                                            \
        cw[m] += (unsigned)__popcll(__ballot(e));    /* scalar pipe */       \
        al[m] += e ? l : 0.f;                                                \
      }                                                                      \
    }
    SLOTP(x, x) SLOTP(y, y) SLOTP(z, z) SLOTP(w, w)
#undef SLOTP
  }

#pragma unroll
  for (int v = 0; v < 16; v++) red[wv][lane][v] = al[v];
  if (lane == 0) {
#pragma unroll
    for (int m = 0; m < MI; m++) cbuf[wv][m] = (float)cw[m];
  }
  __syncthreads();
  if (tid < 32) {
    const int m = tid >> 1, c = tid & 1;
    float s = 0.f;
    if (c == 0) {
#pragma unroll
      for (int w = 0; w < 4; w++)
#pragma unroll 8
        for (int l = 0; l < 64; l++) s += red[w][(l + tid) & 63][m];
    } else {
      s = cbuf[0][m] + cbuf[1][m] + cbuf[2][m] + cbuf[3][m];
    }
    ws[WS_PP + (size_t)(b * GPB + blk) * 32 + tid] = s;   // contiguous per block
  }
}

__global__ void k_final(const float* __restrict__ ws, float* __restrict__ out) {
  __shared__ float gpart[3][80];
  __shared__ float tot80[80];
  __shared__ float part[8][32];
  __shared__ float tot[32];
  __shared__ float sG[MI * 4];
  __shared__ float svalid[MI];
  const int b = blockIdx.x, t = threadIdx.x;   // 256 threads, one block per b

  // ---- G + valid prologue (IDENTICAL summation order to k_pull) ----
  {
    const int v = t % 80, h = t / 80;
    if (h < 2) {
      const float* src = ws + WS_PS + (size_t)(b * GPB + h * 67) * 80 + v;
      float s = 0.f;
#pragma unroll                                  // FULL unroll: independent loads
      for (int k = 0; k < 67; k++) s += src[(size_t)k * 80];
      gpart[h][v] = s;
    } else if (h == 2) {
      const float* src = ws + WS_PS + (size_t)(b * GPB + 134) * 80 + v;
      float s = 0.f;
#pragma unroll                                  // FULL unroll: independent loads
      for (int k = 0; k < 66; k++) s += src[(size_t)k * 80];
      gpart[2][v] = s;
    }
    __syncthreads();
    if (t < 80) tot80[t] = gpart[0][t] + gpart[1][t] + gpart[2][t];
    __syncthreads();
    if (t < MI) {
      const float cntk = tot80[t * 5 + 4];
      const float inv = 1.f / fmaxf(cntk, 1.f);
      sG[t * 4 + 0] = tot80[t * 5 + 0] * inv;
      sG[t * 4 + 1] = tot80[t * 5 + 1] * inv;
      sG[t * 4 + 2] = tot80[t * 5 + 2] * inv;
      sG[t * 4 + 3] = tot80[t * 5 + 3] * inv;
      svalid[t] = (cntk > 0.f && t >= 1) ? 1.f : 0.f;
    }
    __syncthreads();
  }

  // ---- PP reduce ----
  const int v = t & 31, h = t >> 5;            // 8 chunks of 25 blocks
  float s = 0.f;
  const float* src = ws + WS_PP + (size_t)(b * GPB + h * 25) * 32 + v;
#pragma unroll                                  // FULL unroll: independent loads
  for (int k = 0; k < 25; k++) s += src[(size_t)k * 32];
  part[h][v] = s;
  __syncthreads();
  if (t < 32) {
    float x = 0.f;
#pragma unroll
    for (int hh = 0; hh < 8; hh++) x += part[hh][t];
    tot[t] = x;
  }
  __syncthreads();
  if (t == 0) {
    float nv = 0.f;
    for (int m = 0; m < MI; m++) nv += svalid[m];
    float pull = 0.f;
    for (int m = 0; m < MI; m++) {
      const float per = tot[m * 2] / fmaxf(tot[m * 2 + 1], 1.f);
      pull += per * svalid[m];
    }
    pull /= fmaxf(nv, 1.f);
    float push = 0.f;
    for (int i = 0; i < MI; i++) {
      if (svalid[i] == 0.f) continue;
      for (int j = i + 1; j < MI; j++) {
        if (svalid[j] == 0.f) continue;
        float d2 = CEPS;
        for (int c = 0; c < 4; c++) {
          const float df = sG[i * 4 + c] - sG[j * 4 + c];
          d2 += df * df;
        }
        const float dk = sqrtf(d2);
        const float tt = fmaxf(3.f - dk, 0.f);
        push += log1pf(tt * tt);
      }
    }
    const float denom = nv * (nv - 1.f);
    push = (nv > 1.f) ? push / fmaxf(denom, 1.f) : 0.f;
    out[b] = pull;
    out[BB + b] = push;
  }
}

extern "C" void kernel_launch(void* const* d_in, const int* in_sizes, int n_in,
                              void* d_out, int out_size, void* d_ws, size_t ws_size,
                              hipStream_t stream) {
  const float* outputs = (const float*)d_in[0];
  const int* gt_texts = (const int*)d_in[1];
  const int* gt_kernels = (const int*)d_in[2];
  float* ws = (float*)d_ws;
  float* out = (float*)d_out;

  dim3 grid(GPB, BB);
  k_sums<<<grid, TPB, 0, stream>>>(outputs, gt_kernels, ws);
  k_pull<<<grid, TPB, 0, stream>>>(outputs, gt_texts, ws);
  k_final<<<BB, 256, 0, stream>>>(ws, out);
}